// Round 3
// baseline (159.541 us; speedup 1.0000x reference)
//
#include <hip/hip_runtime.h>
#include <hip/hip_bf16.h>

// d[e] = || R[idx_i[e]] - R[idx_j[e]] ||
//
// R2 post-mortem: 6 dword vs 2 dwordx4 gathers/edge -> identical 68us.
// Invariant = L1 line fills (2 random lines/edge, ~3.3 cy/fill measured).
// R3 experiment: nontemporal gathers (no L1 allocate) to bypass the fill
// pipe. Table stays L2-resident (1.6MB < 4MB/XCD).

typedef int   v4i __attribute__((ext_vector_type(4)));
typedef float v4f __attribute__((ext_vector_type(4)));

__global__ __launch_bounds__(256) void pad_R_kernel(
    const float* __restrict__ R, float* __restrict__ R4, int n_atoms)
{
    const int i = blockIdx.x * blockDim.x + threadIdx.x;
    if (i < n_atoms) {
        const float x = R[3 * i + 0];
        const float y = R[3 * i + 1];
        const float z = R[3 * i + 2];
        v4f v = {x, y, z, 0.0f};
        *(v4f*)(R4 + 4 * (size_t)i) = v;
    }
}

__global__ __launch_bounds__(256) void pairwise_dist_kernel(
    const float* __restrict__ R4,
    const int* __restrict__ idx_i,
    const int* __restrict__ idx_j,
    float* __restrict__ out,
    int n_quads)
{
    const int quad = blockIdx.x * blockDim.x + threadIdx.x;
    if (quad >= n_quads) return;

    const v4i a = __builtin_nontemporal_load((const v4i*)idx_i + quad);
    const v4i b = __builtin_nontemporal_load((const v4i*)idx_j + quad);

    // Random-table gathers: nontemporal -> no L1 line allocation.
    const v4f pa0 = __builtin_nontemporal_load((const v4f*)(R4 + 4 * (size_t)a.x));
    const v4f pb0 = __builtin_nontemporal_load((const v4f*)(R4 + 4 * (size_t)b.x));
    const v4f pa1 = __builtin_nontemporal_load((const v4f*)(R4 + 4 * (size_t)a.y));
    const v4f pb1 = __builtin_nontemporal_load((const v4f*)(R4 + 4 * (size_t)b.y));
    const v4f pa2 = __builtin_nontemporal_load((const v4f*)(R4 + 4 * (size_t)a.z));
    const v4f pb2 = __builtin_nontemporal_load((const v4f*)(R4 + 4 * (size_t)b.z));
    const v4f pa3 = __builtin_nontemporal_load((const v4f*)(R4 + 4 * (size_t)a.w));
    const v4f pb3 = __builtin_nontemporal_load((const v4f*)(R4 + 4 * (size_t)b.w));

    v4f o;
    {
        const v4f d = pa0 - pb0;
        o.x = sqrtf(d.x * d.x + d.y * d.y + d.z * d.z);
    }
    {
        const v4f d = pa1 - pb1;
        o.y = sqrtf(d.x * d.x + d.y * d.y + d.z * d.z);
    }
    {
        const v4f d = pa2 - pb2;
        o.z = sqrtf(d.x * d.x + d.y * d.y + d.z * d.z);
    }
    {
        const v4f d = pa3 - pb3;
        o.w = sqrtf(d.x * d.x + d.y * d.y + d.z * d.z);
    }
    __builtin_nontemporal_store(o, (v4f*)out + quad);
}

__global__ __launch_bounds__(64) void pairwise_dist_tail_kernel(
    const float* __restrict__ R4,
    const int* __restrict__ idx_i,
    const int* __restrict__ idx_j,
    float* __restrict__ out,
    int start, int n_edges)
{
    const int e = start + blockIdx.x * blockDim.x + threadIdx.x;
    if (e < n_edges) {
        const v4f pa = *(const v4f*)(R4 + 4 * (size_t)idx_i[e]);
        const v4f pb = *(const v4f*)(R4 + 4 * (size_t)idx_j[e]);
        const v4f d = pa - pb;
        out[e] = sqrtf(d.x * d.x + d.y * d.y + d.z * d.z);
    }
}

extern "C" void kernel_launch(void* const* d_in, const int* in_sizes, int n_in,
                              void* d_out, int out_size, void* d_ws, size_t ws_size,
                              hipStream_t stream)
{
    const float* R     = (const float*)d_in[0];
    const int*   idx_i = (const int*)d_in[1];
    const int*   idx_j = (const int*)d_in[2];
    float*       out   = (float*)d_out;

    const int n_atoms = in_sizes[0] / 3;        // 100,000
    const int n_edges = in_sizes[1];            // 6,400,000
    float*    R4      = (float*)d_ws;           // n_atoms * 4 floats = 1.6 MB

    {
        const int block = 256;
        const int grid  = (n_atoms + block - 1) / block;
        pad_R_kernel<<<grid, block, 0, stream>>>(R, R4, n_atoms);
    }

    const int n_quads = n_edges >> 2;
    {
        const int block = 256;
        const int grid  = (n_quads + block - 1) / block;
        pairwise_dist_kernel<<<grid, block, 0, stream>>>(R4, idx_i, idx_j, out, n_quads);
    }

    const int tail_start = n_quads << 2;
    if (tail_start < n_edges) {
        const int tail = n_edges - tail_start;
        pairwise_dist_tail_kernel<<<(tail + 63) / 64, 64, 0, stream>>>(
            R4, idx_i, idx_j, out, tail_start, n_edges);
    }
}

// Round 4
// 145.054 us; speedup vs baseline: 1.0999x; 1.0999x over previous
//
#include <hip/hip_runtime.h>
#include <hip/hip_bf16.h>

// d[e] = || R[idx_i[e]] - R[idx_j[e]] ||
//
// R1/R2/R3 post-mortem: time invariant (~68us) across 6-dword, 2-dwordx4,
// and nt gathers -> bound by L1 line-fill throughput, 3.26 cy/fill ==
// ~64 MSHRs / ~208cy L2 latency. R4: bypass L1 on table gathers with sc0
// (GLC) so no MSHR/fill is allocated; requests stream to L2 at ~1/cy/CU.
// 8 edges/thread for deep MLP. idx/out are plain coalesced accesses.

typedef int   v4i __attribute__((ext_vector_type(4)));
typedef float v4f __attribute__((ext_vector_type(4)));

__global__ __launch_bounds__(256) void pad_R_kernel(
    const float* __restrict__ R, float* __restrict__ R4, int n_atoms)
{
    const int i = blockIdx.x * blockDim.x + threadIdx.x;
    if (i < n_atoms) {
        const float x = R[3 * i + 0];
        const float y = R[3 * i + 1];
        const float z = R[3 * i + 2];
        v4f v = {x, y, z, 0.0f};
        *(v4f*)(R4 + 4 * (size_t)i) = v;
    }
}

// L1-bypass gather: global_load_dwordx4 with sc0 (device-coherent, no L1
// allocate). saddr form: 64-bit SGPR base + 32-bit VGPR byte offset
// (table is 1.6 MB, so idx*16 always fits in 32 bits).
__device__ __forceinline__ v4f gather_sc0(const float* base, int idx)
{
    v4f r;
    const int voff = idx << 4;
    asm volatile("global_load_dwordx4 %0, %1, %2 sc0"
                 : "=v"(r)
                 : "v"(voff), "s"(base)
                 : "memory");
    return r;
}

__device__ __forceinline__ float dist3(v4f a, v4f b)
{
    const v4f d = a - b;
    return sqrtf(d.x * d.x + d.y * d.y + d.z * d.z);
}

__global__ __launch_bounds__(256) void pairwise_dist_kernel(
    const float* __restrict__ R4,
    const int* __restrict__ idx_i,
    const int* __restrict__ idx_j,
    float* __restrict__ out,
    int n_oct)   // groups of 8 edges
{
    const int t = blockIdx.x * blockDim.x + threadIdx.x;
    if (t >= n_oct) return;

    const v4i a0 = ((const v4i*)idx_i)[2 * t + 0];
    const v4i a1 = ((const v4i*)idx_i)[2 * t + 1];
    const v4i b0 = ((const v4i*)idx_j)[2 * t + 0];
    const v4i b1 = ((const v4i*)idx_j)[2 * t + 1];

    // 16 L1-bypass gathers in flight.
    v4f pa0 = gather_sc0(R4, a0.x), pb0 = gather_sc0(R4, b0.x);
    v4f pa1 = gather_sc0(R4, a0.y), pb1 = gather_sc0(R4, b0.y);
    v4f pa2 = gather_sc0(R4, a0.z), pb2 = gather_sc0(R4, b0.z);
    v4f pa3 = gather_sc0(R4, a0.w), pb3 = gather_sc0(R4, b0.w);
    v4f pa4 = gather_sc0(R4, a1.x), pb4 = gather_sc0(R4, b1.x);
    v4f pa5 = gather_sc0(R4, a1.y), pb5 = gather_sc0(R4, b1.y);
    v4f pa6 = gather_sc0(R4, a1.z), pb6 = gather_sc0(R4, b1.z);
    v4f pa7 = gather_sc0(R4, a1.w), pb7 = gather_sc0(R4, b1.w);

    // Drain all outstanding vmem; tying the loaded regs as in-outs makes
    // every later use data-depend on this wait.
    asm volatile("s_waitcnt vmcnt(0)"
                 : "+v"(pa0), "+v"(pb0), "+v"(pa1), "+v"(pb1),
                   "+v"(pa2), "+v"(pb2), "+v"(pa3), "+v"(pb3),
                   "+v"(pa4), "+v"(pb4), "+v"(pa5), "+v"(pb5),
                   "+v"(pa6), "+v"(pb6), "+v"(pa7), "+v"(pb7)
                 :
                 : "memory");

    v4f o0, o1;
    o0.x = dist3(pa0, pb0);
    o0.y = dist3(pa1, pb1);
    o0.z = dist3(pa2, pb2);
    o0.w = dist3(pa3, pb3);
    o1.x = dist3(pa4, pb4);
    o1.y = dist3(pa5, pb5);
    o1.z = dist3(pa6, pb6);
    o1.w = dist3(pa7, pb7);

    ((v4f*)out)[2 * t + 0] = o0;
    ((v4f*)out)[2 * t + 1] = o1;
}

__global__ __launch_bounds__(64) void pairwise_dist_tail_kernel(
    const float* __restrict__ R4,
    const int* __restrict__ idx_i,
    const int* __restrict__ idx_j,
    float* __restrict__ out,
    int start, int n_edges)
{
    const int e = start + blockIdx.x * blockDim.x + threadIdx.x;
    if (e < n_edges) {
        const v4f pa = *(const v4f*)(R4 + 4 * (size_t)idx_i[e]);
        const v4f pb = *(const v4f*)(R4 + 4 * (size_t)idx_j[e]);
        out[e] = dist3(pa, pb);
    }
}

extern "C" void kernel_launch(void* const* d_in, const int* in_sizes, int n_in,
                              void* d_out, int out_size, void* d_ws, size_t ws_size,
                              hipStream_t stream)
{
    const float* R     = (const float*)d_in[0];
    const int*   idx_i = (const int*)d_in[1];
    const int*   idx_j = (const int*)d_in[2];
    float*       out   = (float*)d_out;

    const int n_atoms = in_sizes[0] / 3;        // 100,000
    const int n_edges = in_sizes[1];            // 6,400,000
    float*    R4      = (float*)d_ws;           // n_atoms * 4 floats = 1.6 MB

    {
        const int block = 256;
        const int grid  = (n_atoms + block - 1) / block;
        pad_R_kernel<<<grid, block, 0, stream>>>(R, R4, n_atoms);
    }

    const int n_oct = n_edges >> 3;             // 800,000 (exact for 6.4M)
    {
        const int block = 256;
        const int grid  = (n_oct + block - 1) / block;
        pairwise_dist_kernel<<<grid, block, 0, stream>>>(R4, idx_i, idx_j, out, n_oct);
    }

    const int tail_start = n_oct << 3;
    if (tail_start < n_edges) {
        const int tail = n_edges - tail_start;
        pairwise_dist_tail_kernel<<<(tail + 63) / 64, 64, 0, stream>>>(
            R4, idx_i, idx_j, out, tail_start, n_edges);
    }
}